// Round 20
// baseline (51.365 us; speedup 1.0000x reference)
//
#include <hip/hip_runtime.h>
#include <cstdint>
#include <cstddef>

#define NB 8
#define NG 64
#define NP 50000
#define CH 2000                  // preds per chunk (25*2000 = NP exactly)
#define NCH 25                   // p-chunks
#define NGG 8                    // g-groups of 8
#define NNEG4 ((NB * NP / 4 + 255) / 256)  // 391 neg-combine blocks

__device__ __forceinline__ void opaque(float& x) { asm volatile("" : "+v"(x)); }
__device__ __forceinline__ unsigned long long umax64(unsigned long long a, unsigned long long b) {
    return a > b ? a : b;
}

// ---------------------------------------------------------------------------
// UNIFIED row-oriented kernel (R18/R19-proven): each iou computed exactly once.
// R20 change: 4 preds per loop iteration + float4 stores, SAME 1600-block grid
// (previous 4-wide attempts lost because they shrank the grid; here TLP is
// unchanged and only store-instruction count halves).
__global__ __launch_bounds__(256) void unified(
    const float* __restrict__ pred,
    const float* __restrict__ gt,
    float* __restrict__ out_iou,
    float* __restrict__ out_pos,
    unsigned char* __restrict__ negpart,
    unsigned long long* __restrict__ part)
{
    __shared__ float s_gx0[8], s_gy0[8], s_gx1[8], s_gy1[8], s_ga[8];
    const int b  = blockIdx.z;
    const int gg = blockIdx.y;
    const int p0 = blockIdx.x * CH;
    const int tid = threadIdx.x;

    if (tid < 8) {
        const float4 gb = reinterpret_cast<const float4*>(gt)[b * NG + gg * 8 + tid];
        float hw = 0.5f * gb.z, hh = 0.5f * gb.w;   // exact, FMA-safe
        float x0 = gb.x - hw, y0 = gb.y - hh;
        float x1 = gb.x + hw, y1 = gb.y + hh;
        float ga = (x1 - x0) * (y1 - y0);
        opaque(ga);
        s_gx0[tid] = x0; s_gy0[tid] = y0;
        s_gx1[tid] = x1; s_gy1[tid] = y1;
        s_ga[tid]  = ga;
    }
    __syncthreads();

    float        bv[8] = {-1.f,-1.f,-1.f,-1.f,-1.f,-1.f,-1.f,-1.f};
    unsigned int bp[8] = {0,0,0,0,0,0,0,0};

    #pragma unroll 1
    for (int idx = tid; idx < CH / 4; idx += 256) {   // 500 pred-quads
        const int p = p0 + 4 * idx;

        float px0[4], py0[4], px1[4], py1[4], pa[4];
        #pragma unroll
        for (int k = 0; k < 4; ++k) {
            const float4 pb = reinterpret_cast<const float4*>(pred)[(size_t)b * NP + p + k];
            float hw = 0.5f * pb.z, hh = 0.5f * pb.w;
            px0[k] = pb.x - hw; py0[k] = pb.y - hh;
            px1[k] = pb.x + hw; py1[k] = pb.y + hh;
            float a = (px1[k] - px0[k]) * (py1[k] - py0[k]);
            opaque(a);
            pa[k] = a;
        }

        float cmax[4] = {0.0f, 0.0f, 0.0f, 0.0f};
        const size_t rbase = (size_t)b * NG * NP + (size_t)(gg * 8) * NP + (size_t)p;

        #pragma unroll
        for (int j = 0; j < 8; ++j) {
            const float gx0 = s_gx0[j], gy0 = s_gy0[j];
            const float gx1 = s_gx1[j], gy1 = s_gy1[j];
            const float ga  = s_ga[j];

            float iou[4];
            #pragma unroll
            for (int k = 0; k < 4; ++k) {
                float w = fmaxf(fminf(gx1, px1[k]) - fmaxf(gx0, px0[k]), 0.0f);
                float h = fmaxf(fminf(gy1, py1[k]) - fmaxf(gy0, py0[k]), 0.0f);
                float inter = w * h;
                opaque(inter);                       // numpy op order: (ga+pa)-inter
                iou[k] = inter / ((ga + pa[k]) - inter);  // IEEE div
                cmax[k] = fmaxf(cmax[k], iou[k]);
            }

            float4 vi; vi.x = iou[0]; vi.y = iou[1]; vi.z = iou[2]; vi.w = iou[3];
            *reinterpret_cast<float4*>(out_iou + rbase + (size_t)j * NP) = vi;

            float4 vp;
            vp.x = (iou[0] > 0.7f) ? 1.0f : 0.0f;
            vp.y = (iou[1] > 0.7f) ? 1.0f : 0.0f;
            vp.z = (iou[2] > 0.7f) ? 1.0f : 0.0f;
            vp.w = (iou[3] > 0.7f) ? 1.0f : 0.0f;
            *reinterpret_cast<float4*>(out_pos + rbase + (size_t)j * NP) = vp;

            // argmax accumulate: strict >, ascending p -> first occurrence
            if (iou[0] > bv[j]) { bv[j] = iou[0]; bp[j] = (unsigned int)p; }
            if (iou[1] > bv[j]) { bv[j] = iou[1]; bp[j] = (unsigned int)(p + 1); }
            if (iou[2] > bv[j]) { bv[j] = iou[2]; bp[j] = (unsigned int)(p + 2); }
            if (iou[3] > bv[j]) { bv[j] = iou[3]; bp[j] = (unsigned int)(p + 3); }
        }

        uchar4 fl;                                   // 1 iff group-max < 0.3
        fl.x = (cmax[0] < 0.3f) ? 1 : 0;
        fl.y = (cmax[1] < 0.3f) ? 1 : 0;
        fl.z = (cmax[2] < 0.3f) ? 1 : 0;
        fl.w = (cmax[3] < 0.3f) ? 1 : 0;
        *reinterpret_cast<uchar4*>(negpart + ((size_t)b * NGG + gg) * NP + p) = fl;
    }

    // per-block argmax reduction: butterfly within wave, LDS across 4 waves
    __shared__ unsigned long long s_part[8][4];
    const int lane = tid & 63;
    const int wv = tid >> 6;
    #pragma unroll
    for (int j = 0; j < 8; ++j) {
        unsigned long long k = 0;
        if (bv[j] >= 0.0f)
            k = ((unsigned long long)__float_as_uint(bv[j]) << 32) |
                (unsigned long long)(0xFFFFFFFFu - bp[j]);
        #pragma unroll
        for (int s = 1; s < 64; s <<= 1)
            k = umax64(k, __shfl_xor(k, s, 64));
        if (lane == 0) s_part[j][wv] = k;
    }
    __syncthreads();

    if (tid < 8) {
        unsigned long long r = umax64(umax64(s_part[tid][0], s_part[tid][1]),
                                      umax64(s_part[tid][2], s_part[tid][3]));
        part[((size_t)b * NG + (size_t)(gg * 8 + tid)) * NCH + blockIdx.x] = r;
    }
}

// Combined fixup: blocks [0,NNEG4) AND 8 flag slabs -> neg; last 2 blocks
// reduce 25 partial keys per row and set the argmax bit in pos.
__global__ __launch_bounds__(256) void fix_combined(
    const unsigned long long* __restrict__ part,
    const unsigned char* __restrict__ negpart,
    float* __restrict__ out_pos,
    float* __restrict__ out_neg)
{
    const int bid = blockIdx.x;
    const int tid = threadIdx.x;

    if (bid < NNEG4) {
        const int idx = bid * 256 + tid;             // float4 index over NB*NP/4
        if (idx < NB * (NP / 4)) {
            const int b = idx / (NP / 4);
            const int p = 4 * (idx % (NP / 4));
            uchar4 m = *reinterpret_cast<const uchar4*>(negpart + ((size_t)b * NGG + 0) * NP + p);
            #pragma unroll
            for (int gg = 1; gg < NGG; ++gg) {
                const uchar4 t = *reinterpret_cast<const uchar4*>(negpart + ((size_t)b * NGG + gg) * NP + p);
                m.x &= t.x; m.y &= t.y; m.z &= t.z; m.w &= t.w;
            }
            float4 vn;
            vn.x = m.x ? 1.0f : 0.0f;
            vn.y = m.y ? 1.0f : 0.0f;
            vn.z = m.z ? 1.0f : 0.0f;
            vn.w = m.w ? 1.0f : 0.0f;
            *reinterpret_cast<float4*>(out_neg + (size_t)b * NP + p) = vn;
        }
    } else {
        const int row = (bid - NNEG4) * 256 + tid;   // b*NG + g
        if (row < NB * NG) {
            const unsigned long long* pr = part + (size_t)row * NCH;
            unsigned long long r = pr[0];
            #pragma unroll
            for (int c = 1; c < NCH; ++c) r = umax64(r, pr[c]);
            unsigned int idx = 0xFFFFFFFFu - (unsigned int)(r & 0xFFFFFFFFull);
            if (idx < NP) out_pos[(size_t)row * NP + idx] = 1.0f;
        }
    }
}

// ------------------- fallback path (ws too small): R3-proven -------------------
__global__ __launch_bounds__(256) void stream2_full(
    const float* __restrict__ pred,
    const float* __restrict__ gt,
    float* __restrict__ out_iou,
    float* __restrict__ out_pos,
    float* __restrict__ out_neg)
{
    __shared__ float s_gx0[NG], s_gy0[NG], s_gx1[NG], s_gy1[NG], s_ga[NG];
    const int b = blockIdx.y;
    const int tid = threadIdx.x;
    if (tid < NG) {
        const float4 gb = reinterpret_cast<const float4*>(gt)[b * NG + tid];
        float hw = 0.5f * gb.z, hh = 0.5f * gb.w;
        float x0 = gb.x - hw, y0 = gb.y - hh;
        float x1 = gb.x + hw, y1 = gb.y + hh;
        float ga = (x1 - x0) * (y1 - y0);
        opaque(ga);
        s_gx0[tid] = x0; s_gy0[tid] = y0;
        s_gx1[tid] = x1; s_gy1[tid] = y1;
        s_ga[tid]  = ga;
    }
    __syncthreads();
    const int p = 2 * (blockIdx.x * 256 + tid);
    if (p >= NP) return;
    const float4 pb0 = reinterpret_cast<const float4*>(pred)[(size_t)b * NP + p];
    const float4 pb1 = reinterpret_cast<const float4*>(pred)[(size_t)b * NP + p + 1];
    float hw0 = 0.5f * pb0.z, hh0 = 0.5f * pb0.w;
    const float ax0 = pb0.x - hw0, ay0 = pb0.y - hh0;
    const float ax1 = pb0.x + hw0, ay1 = pb0.y + hh0;
    float pa0 = (ax1 - ax0) * (ay1 - ay0); opaque(pa0);
    float hw1 = 0.5f * pb1.z, hh1 = 0.5f * pb1.w;
    const float bx0 = pb1.x - hw1, by0 = pb1.y - hh1;
    const float bx1 = pb1.x + hw1, by1 = pb1.y + hh1;
    float pa1 = (bx1 - bx0) * (by1 - by0); opaque(pa1);
    float maxv0 = 0.0f, maxv1 = 0.0f;
    const size_t base = (size_t)b * NG * NP + (size_t)p;
    #pragma unroll 8
    for (int g = 0; g < NG; ++g) {
        const float gx0 = s_gx0[g], gy0 = s_gy0[g];
        const float gx1 = s_gx1[g], gy1 = s_gy1[g];
        const float ga  = s_ga[g];
        float w0 = fmaxf(fminf(gx1, ax1) - fmaxf(gx0, ax0), 0.0f);
        float h0 = fmaxf(fminf(gy1, ay1) - fmaxf(gy0, ay0), 0.0f);
        float inter0 = w0 * h0; opaque(inter0);
        float iou0 = inter0 / ((ga + pa0) - inter0);
        float w1 = fmaxf(fminf(gx1, bx1) - fmaxf(gx0, bx0), 0.0f);
        float h1 = fmaxf(fminf(gy1, by1) - fmaxf(gy0, by0), 0.0f);
        float inter1 = w1 * h1; opaque(inter1);
        float iou1 = inter1 / ((ga + pa1) - inter1);
        float2 vi; vi.x = iou0; vi.y = iou1;
        *reinterpret_cast<float2*>(out_iou + base + (size_t)g * NP) = vi;
        float2 vp; vp.x = (iou0 > 0.7f) ? 1.0f : 0.0f;
                   vp.y = (iou1 > 0.7f) ? 1.0f : 0.0f;
        *reinterpret_cast<float2*>(out_pos + base + (size_t)g * NP) = vp;
        maxv0 = fmaxf(maxv0, iou0);
        maxv1 = fmaxf(maxv1, iou1);
    }
    float2 vn; vn.x = (maxv0 < 0.3f) ? 1.0f : 0.0f;
               vn.y = (maxv1 < 0.3f) ? 1.0f : 0.0f;
    *reinterpret_cast<float2*>(out_neg + (size_t)b * NP + p) = vn;
}

__global__ __launch_bounds__(256) void argmax_scan(
    const float* __restrict__ out_iou,
    float* __restrict__ out_pos)
{
    const int row = blockIdx.x;
    const float4* r4 = reinterpret_cast<const float4*>(out_iou + (size_t)row * NP);
    float bv = -1.0f;
    int   bi = 0x7fffffff;
    for (int c = threadIdx.x; c < NP / 4; c += 256) {
        float4 v = r4[c];
        int p = 4 * c;
        if (v.x > bv) { bv = v.x; bi = p; }
        if (v.y > bv) { bv = v.y; bi = p + 1; }
        if (v.z > bv) { bv = v.z; bi = p + 2; }
        if (v.w > bv) { bv = v.w; bi = p + 3; }
    }
    #pragma unroll
    for (int s = 1; s < 64; s <<= 1) {
        float ov = __shfl_xor(bv, s, 64);
        int   oi = __shfl_xor(bi, s, 64);
        if (ov > bv || (ov == bv && oi < bi)) { bv = ov; bi = oi; }
    }
    __shared__ float sv[4];
    __shared__ int   si[4];
    const int wid = threadIdx.x >> 6;
    if ((threadIdx.x & 63) == 0) { sv[wid] = bv; si[wid] = bi; }
    __syncthreads();
    if (threadIdx.x == 0) {
        for (int w = 1; w < 4; ++w)
            if (sv[w] > bv || (sv[w] == bv && si[w] < bi)) { bv = sv[w]; bi = si[w]; }
        out_pos[(size_t)row * NP + bi] = 1.0f;
    }
}

extern "C" void kernel_launch(void* const* d_in, const int* in_sizes, int n_in,
                              void* d_out, int out_size, void* d_ws, size_t ws_size,
                              hipStream_t stream) {
    const float* pred = (const float*)d_in[0];
    const float* gt   = (const float*)d_in[1];
    float* out_iou = (float*)d_out;
    float* out_pos = out_iou + (size_t)NB * NG * NP;
    float* out_neg = out_pos + (size_t)NB * NG * NP;

    const size_t part_bytes = (size_t)NB * NG * NCH * sizeof(unsigned long long);  // 102 KB
    const size_t neg_bytes  = (size_t)NB * NGG * NP;                               // 3.2 MB (u8)

    if (ws_size >= part_bytes + neg_bytes) {
        unsigned long long* part = (unsigned long long*)d_ws;
        unsigned char* negpart = (unsigned char*)d_ws + part_bytes;
        unified<<<dim3(NCH, NGG, NB), dim3(256), 0, stream>>>(
            pred, gt, out_iou, out_pos, negpart, part);
        fix_combined<<<dim3(NNEG4 + 2), dim3(256), 0, stream>>>(part, negpart, out_pos, out_neg);
    } else {
        stream2_full<<<dim3(98, NB), dim3(256), 0, stream>>>(pred, gt, out_iou, out_pos, out_neg);
        argmax_scan<<<dim3(NB * NG), dim3(256), 0, stream>>>(out_iou, out_pos);
    }
}